// Round 3
// baseline (101.617 us; speedup 1.0000x reference)
//
#include <hip/hip_runtime.h>
#include <math.h>

#define NSM 4
#define NCELL 64
#define SC_GRID 1024
#define GA_GRID 2048

// ---------- helpers ----------

__device__ __forceinline__ void inv3x3(const float* __restrict__ C, float* inv) {
    float a=C[0],b=C[1],c=C[2],d=C[3],e=C[4],f=C[5],g=C[6],h=C[7],i=C[8];
    float A  =  (e*i - f*h);
    float B  = -(d*i - f*g);
    float Cc =  (d*h - e*g);
    float det = a*A + b*B + c*Cc;
    float rd = 1.0f/det;
    inv[0] = A*rd;
    inv[1] = (c*h - b*i)*rd;
    inv[2] = (b*f - c*e)*rd;
    inv[3] = B*rd;
    inv[4] = (a*i - c*g)*rd;
    inv[5] = (c*d - a*f)*rd;
    inv[6] = Cc*rd;
    inv[7] = (b*g - a*h)*rd;
    inv[8] = (a*e - b*d)*rd;
}

// 4-wide periodic M3 weights, branch-free via compares (no dynamic indexing).
// Grid point j gets: w0 if j==n0, wm if j==(n0-1)&3, wp if j==(n0+1)&3, else 0.
__device__ __forceinline__ void axis_weights4(float u, float* __restrict__ W) {
    float nf = rintf(u);            // ties differ from floor(u+0.5) only where
    float x  = u - nf;              // the weight sets coincide (continuity)
    float x2 = x*x;
    float w0 = 0.75f - x2;
    float tm = 0.5f - x;
    float tp = 0.5f + x;
    float wm = 0.5f*tm*tm;
    float wp = 0.5f*tp*tp;
    int n0 = ((int)nf) & 3;
    #pragma unroll
    for (int j = 0; j < 4; j++) {
        float w = (n0 == j)         ? w0 : 0.0f;
        w       = (n0 == ((j+1)&3)) ? wm : w;
        w       = (n0 == ((j+3)&3)) ? wp : w;
        W[j] = w;
    }
}

__device__ __forceinline__ float fast_tanh(float x) {
    float ax = fabsf(x);
    float e  = __expf(-2.0f*ax);
    float t  = __fdividef(1.0f - e, 1.0f + e);
    return copysignf(t, x);
}

// ---------- kernel A: scatter via per-thread register mesh ----------

__global__ __launch_bounds__(256) void scatter_kernel(
        const float* __restrict__ pos, const float* __restrict__ cell,
        const float* __restrict__ charges, float* __restrict__ mesh_out, int N) {
    __shared__ float red[128 * 64];            // 32 KB, [row][cell^(row&31)]
    float ci[9]; inv3x3(cell, ci);

    float macc[64];
    #pragma unroll
    for (int i = 0; i < 64; i++) macc[i] = 0.0f;

    int tid    = blockIdx.x * blockDim.x + threadIdx.x;
    int stride = gridDim.x * blockDim.x;

    for (int n = tid; n < N; n += stride) {
        float px = pos[3*n], py = pos[3*n+1], pz = pos[3*n+2];
        float q  = charges[n];
        float fx = px*ci[0] + py*ci[3] + pz*ci[6];
        float fy = px*ci[1] + py*ci[4] + pz*ci[7];
        float fz = px*ci[2] + py*ci[5] + pz*ci[8];
        float X[4], Y[4], Z[4];
        axis_weights4(fx*(float)NSM, X);
        axis_weights4(fy*(float)NSM, Y);
        axis_weights4(fz*(float)NSM, Z);
        float qX[4];
        #pragma unroll
        for (int x = 0; x < 4; x++) qX[x] = q * X[x];
        #pragma unroll
        for (int x = 0; x < 4; x++) {
            #pragma unroll
            for (int y = 0; y < 4; y++) {
                float wxy = qX[x] * Y[y];
                #pragma unroll
                for (int z = 0; z < 4; z++)
                    macc[x*16 + y*4 + z] = fmaf(wxy, Z[z], macc[x*16 + y*4 + z]);
            }
        }
    }

    // two-phase staged reduction in 32 KB
    int t = threadIdx.x;
    if (t < 128) {
        int sw = t & 31;
        #pragma unroll
        for (int c = 0; c < 64; c++) red[t*64 + (c ^ sw)] = macc[c];
    }
    __syncthreads();
    if (t >= 128) {
        int tt = t - 128;
        int sw = tt & 31;
        #pragma unroll
        for (int c = 0; c < 64; c++) red[tt*64 + (c ^ sw)] += macc[c];
    }
    __syncthreads();
    // reduce 128 rows: group g handles rows g*32..g*32+31 for cell cl
    int cl = t & 63, g = t >> 6;
    float sum = 0.0f;
    #pragma unroll
    for (int i = 0; i < 32; i++) {
        int r = g*32 + i;
        sum += red[r*64 + (cl ^ (r & 31))];
    }
    __syncthreads();
    red[t] = sum;
    __syncthreads();
    if (t < NCELL) {
        float v = red[t] + red[64 + t] + red[128 + t] + red[192 + t];
        unsafeAtomicAdd(&mesh_out[t], v);
    }
}

// ---------- kernel B: k-space filter as real circular convolution ----------
// (backward-norm rfft + forward-norm irfft => no 1/64 factor)

__global__ void filter_kernel(const float* __restrict__ cell,
                              const float* __restrict__ sigma2p,
                              const float* __restrict__ mesh_in,
                              float* __restrict__ mesh_out,
                              float* __restrict__ out_zero) {
    __shared__ float gr[64];
    __shared__ float mm[64];
    int t = threadIdx.x;            // 0..63
    float ci[9]; inv3x3(cell, ci);
    float s2 = sigma2p[0];
    const float twopi = 6.2831853071795864769f;
    float G0x = twopi*ci[0], G0y = twopi*ci[3], G0z = twopi*ci[6];
    float G1x = twopi*ci[1], G1y = twopi*ci[4], G1z = twopi*ci[7];
    float G2x = twopi*ci[2], G2y = twopi*ci[5], G2z = twopi*ci[8];

    mm[t] = mesh_in[t];
    int dx = t >> 4, dy = (t >> 2) & 3, dz = t & 3;
    float acc = 0.0f;
    for (int a = 0; a < 4; a++) {
        float fa = (a < 2) ? (float)a : (float)(a - 4);
        for (int b = 0; b < 4; b++) {
            float fb = (b < 2) ? (float)b : (float)(b - 4);
            for (int c = 0; c < 4; c++) {
                if ((a | b | c) == 0) continue;
                float fc = (c < 2) ? (float)c : (float)(c - 4);
                float kx = fa*G0x + fb*G1x + fc*G2x;
                float ky = fa*G0y + fb*G1y + fc*G2y;
                float kz = fa*G0z + fb*G1z + fc*G2z;
                float k2 = kx*kx + ky*ky + kz*kz;
                float K  = expf(-k2 * s2 * 0.5f) / k2;
                int ph = (a*dx + b*dy + c*dz) & 3;
                float cs = (ph == 0) ? 1.0f : ((ph == 2) ? -1.0f : 0.0f);
                acc += K * cs;
            }
        }
    }
    gr[t] = acc;
    __syncthreads();
    float o = 0.0f;
    for (int s = 0; s < 64; s++) {
        int sx = s >> 4, sy = (s >> 2) & 3, sz = s & 3;
        int d = ((dx - sx) & 3)*16 + ((dy - sy) & 3)*4 + ((dz - sz) & 3);
        o += gr[d] * mm[s];
    }
    mesh_out[t] = o;
    if (t == 0) out_zero[0] = 0.0f;   // zero scalar output before gather adds
}

// ---------- kernel C: gather (dense separable) + MLP + global sum ----------

__global__ __launch_bounds__(256) void gather_mlp_kernel(
        const float* __restrict__ pos, const float* __restrict__ cell,
        const float* __restrict__ charges,
        const float* __restrict__ W1, const float* __restrict__ b1,
        const float* __restrict__ W2, const float* __restrict__ b2,
        const float* __restrict__ W3, const float* __restrict__ b3,
        const float* __restrict__ meshf, float* __restrict__ out, int N) {
    __shared__ float4 mf4[16];                 // mesh rows m[x][y][0..3]
    __shared__ float wavesum[4];
    if (threadIdx.x < 16) mf4[threadIdx.x] = ((const float4*)meshf)[threadIdx.x];
    float ci[9]; inv3x3(cell, ci);

    float w1r0[10], w1r1[10], b1r[10], w2r[10][10], b2r[10], w3r[10];
    #pragma unroll
    for (int j = 0; j < 10; j++) {
        w1r0[j] = W1[j]; w1r1[j] = W1[10 + j];
        b1r[j] = b1[j];  b2r[j] = b2[j]; w3r[j] = W3[j];
    }
    #pragma unroll
    for (int i = 0; i < 10; i++) {
        #pragma unroll
        for (int j = 0; j < 10; j++) w2r[i][j] = W2[10*i + j];
    }
    float b3r = b3[0];
    __syncthreads();

    int tid    = blockIdx.x * blockDim.x + threadIdx.x;
    int stride = gridDim.x * blockDim.x;
    float ysum = 0.0f;

    for (int n = tid; n < N; n += stride) {
        float px = pos[3*n], py = pos[3*n+1], pz = pos[3*n+2];
        float q  = charges[n];
        float fx = px*ci[0] + py*ci[3] + pz*ci[6];
        float fy = px*ci[1] + py*ci[4] + pz*ci[7];
        float fz = px*ci[2] + py*ci[5] + pz*ci[8];
        float X[4], Y[4], Z[4];
        axis_weights4(fx*(float)NSM, X);
        axis_weights4(fy*(float)NSM, Y);
        axis_weights4(fz*(float)NSM, Z);

        // dense separable contraction: 16 uniform ds_read_b128 + 84 FMA
        float pot = 0.0f;
        #pragma unroll
        for (int x = 0; x < 4; x++) {
            float sx = 0.0f;
            #pragma unroll
            for (int y = 0; y < 4; y++) {
                float4 v = mf4[x*4 + y];
                float sxy = Z[0]*v.x;
                sxy = fmaf(Z[1], v.y, sxy);
                sxy = fmaf(Z[2], v.z, sxy);
                sxy = fmaf(Z[3], v.w, sxy);
                sx  = fmaf(Y[y], sxy, sx);
            }
            pot = fmaf(X[x], sx, pot);
        }

        float h1[10], h2[10];
        #pragma unroll
        for (int j = 0; j < 10; j++)
            h1[j] = fast_tanh(q*w1r0[j] + pot*w1r1[j] + b1r[j]);
        #pragma unroll
        for (int j = 0; j < 10; j++) {
            float acc = b2r[j];
            #pragma unroll
            for (int i = 0; i < 10; i++) acc += h1[i]*w2r[i][j];
            h2[j] = fast_tanh(acc);
        }
        float y = b3r;
        #pragma unroll
        for (int j = 0; j < 10; j++) y += h2[j]*w3r[j];
        ysum += y;
    }

    // wave reduce (64 lanes)
    ysum += __shfl_down(ysum, 32);
    ysum += __shfl_down(ysum, 16);
    ysum += __shfl_down(ysum, 8);
    ysum += __shfl_down(ysum, 4);
    ysum += __shfl_down(ysum, 2);
    ysum += __shfl_down(ysum, 1);
    int wid  = threadIdx.x >> 6;
    int lane = threadIdx.x & 63;
    if (lane == 0) wavesum[wid] = ysum;
    __syncthreads();
    if (threadIdx.x == 0) {
        float tsum = wavesum[0] + wavesum[1] + wavesum[2] + wavesum[3];
        unsafeAtomicAdd(out, tsum);
    }
}

// ---------- launch ----------

extern "C" void kernel_launch(void* const* d_in, const int* in_sizes, int n_in,
                              void* d_out, int out_size, void* d_ws, size_t ws_size,
                              hipStream_t stream) {
    const float* pos     = (const float*)d_in[0];
    const float* cell    = (const float*)d_in[1];
    const float* charges = (const float*)d_in[2];
    const float* sigma2  = (const float*)d_in[3];
    const float* W1 = (const float*)d_in[4];
    const float* b1 = (const float*)d_in[5];
    const float* W2 = (const float*)d_in[6];
    const float* b2 = (const float*)d_in[7];
    const float* W3 = (const float*)d_in[8];
    const float* b3 = (const float*)d_in[9];
    int N = in_sizes[2];                 // charges (N,1)

    float* mesh  = (float*)d_ws;         // 64 floats
    float* meshf = mesh + 64;            // 64 floats

    hipMemsetAsync(mesh, 0, NCELL*sizeof(float), stream);

    scatter_kernel<<<SC_GRID, 256, 0, stream>>>(pos, cell, charges, mesh, N);
    filter_kernel<<<1, 64, 0, stream>>>(cell, sigma2, mesh, meshf, (float*)d_out);
    gather_mlp_kernel<<<GA_GRID, 256, 0, stream>>>(pos, cell, charges,
                                                   W1, b1, W2, b2, W3, b3,
                                                   meshf, (float*)d_out, N);
}

// Round 5
// 70.505 us; speedup vs baseline: 1.4413x; 1.4413x over previous
//
#include <hip/hip_runtime.h>
#include <math.h>

#define NSM 4
#define NCELL 64

typedef float f32x2 __attribute__((ext_vector_type(2)));

// ---------- helpers ----------

__device__ __forceinline__ f32x2 splat2(float s) { f32x2 v; v.x = s; v.y = s; return v; }

__device__ __forceinline__ f32x2 pkfma(f32x2 a, f32x2 b, f32x2 c) {
#if __has_builtin(__builtin_elementwise_fma)
    return __builtin_elementwise_fma(a, b, c);
#else
    f32x2 r; r.x = fmaf(a.x, b.x, c.x); r.y = fmaf(a.y, b.y, c.y); return r;
#endif
}

__device__ __forceinline__ void inv3x3(const float* __restrict__ C, float* inv) {
    float a=C[0],b=C[1],c=C[2],d=C[3],e=C[4],f=C[5],g=C[6],h=C[7],i=C[8];
    float A  =  (e*i - f*h);
    float B  = -(d*i - f*g);
    float Cc =  (d*h - e*g);
    float det = a*A + b*B + c*Cc;
    float rd = 1.0f/det;
    inv[0] = A*rd;        inv[1] = (c*h - b*i)*rd; inv[2] = (b*f - c*e)*rd;
    inv[3] = B*rd;        inv[4] = (a*i - c*g)*rd; inv[5] = (c*d - a*f)*rd;
    inv[6] = Cc*rd;       inv[7] = (b*g - a*h)*rd; inv[8] = (a*e - b*d)*rd;
}

// 4-wide periodic M3 weights, branch-free compares (all-static indexing).
__device__ __forceinline__ void axis_w4(float u, float* __restrict__ W) {
    float nf = rintf(u);
    float x  = u - nf;
    float x2 = x*x;
    float w0 = 0.75f - x2;
    float tm = 0.5f - x, tp = 0.5f + x;
    float wm = 0.5f*tm*tm, wp = 0.5f*tp*tp;
    int n0 = ((int)nf) & 3;
    #pragma unroll
    for (int j = 0; j < 4; j++) {
        float w = (n0 == j)         ? w0 : 0.0f;
        w       = (n0 == ((j+1)&3)) ? wm : w;
        w       = (n0 == ((j+3)&3)) ? wp : w;
        W[j] = w;
    }
}

// tanh(x) = 1 - 2/(e^{2x}+1): exact at +-inf, branch-free.
__device__ __forceinline__ float tanh1(float x) {
    float e = __expf(x + x);
    return fmaf(-2.0f, __builtin_amdgcn_rcpf(e + 1.0f), 1.0f);
}
__device__ __forceinline__ f32x2 tanh2v(f32x2 v) {
    float e0 = __expf(v.x + v.x);
    float e1 = __expf(v.y + v.y);
    f32x2 r;
    r.x = fmaf(-2.0f, __builtin_amdgcn_rcpf(e0 + 1.0f), 1.0f);
    r.y = fmaf(-2.0f, __builtin_amdgcn_rcpf(e1 + 1.0f), 1.0f);
    return r;
}

// ---------- kernel A: scatter via per-thread register mesh (no atomics) ----------

__device__ __forceinline__ void scatter_one(float px, float py, float pz, float q,
                                            const float* __restrict__ ci,
                                            f32x2* __restrict__ macc) {
    float fx = px*ci[0] + py*ci[3] + pz*ci[6];
    float fy = px*ci[1] + py*ci[4] + pz*ci[7];
    float fz = px*ci[2] + py*ci[5] + pz*ci[8];
    float X[4], Y[4], Z[4];
    axis_w4(fx*(float)NSM, X);
    axis_w4(fy*(float)NSM, Y);
    axis_w4(fz*(float)NSM, Z);
    f32x2 z01; z01.x = Z[0]; z01.y = Z[1];
    f32x2 z23; z23.x = Z[2]; z23.y = Z[3];
    float qX[4];
    #pragma unroll
    for (int x = 0; x < 4; x++) qX[x] = q * X[x];
    #pragma unroll
    for (int x = 0; x < 4; x++) {
        #pragma unroll
        for (int y = 0; y < 4; y++) {
            f32x2 w2 = splat2(qX[x] * Y[y]);
            macc[x*8 + y*2    ] = pkfma(w2, z01, macc[x*8 + y*2    ]);
            macc[x*8 + y*2 + 1] = pkfma(w2, z23, macc[x*8 + y*2 + 1]);
        }
    }
}

__global__ __launch_bounds__(256) void scatter_kernel(
        const float* __restrict__ pos, const float* __restrict__ cell,
        const float* __restrict__ charges, float* __restrict__ partial, int N) {
    __shared__ f32x2 red[128][32];   // 32 KB
    __shared__ f32x2 red2[8][32];    // 2 KB
    float ci[9]; inv3x3(cell, ci);

    f32x2 macc[32];
    #pragma unroll
    for (int c = 0; c < 32; c++) macc[c] = splat2(0.0f);

    const float4* posv = (const float4*)pos;
    const float4* qv   = (const float4*)charges;
    int tid     = blockIdx.x * blockDim.x + threadIdx.x;
    int stride4 = gridDim.x * blockDim.x;

    for (long b = tid; b * 4 < (long)N; b += stride4) {
        long i = b * 4;
        if (i + 3 < N) {
            float4 p0 = posv[3*b], p1 = posv[3*b+1], p2 = posv[3*b+2];
            float4 q4 = qv[b];
            scatter_one(p0.x, p0.y, p0.z, q4.x, ci, macc);
            scatter_one(p0.w, p1.x, p1.y, q4.y, ci, macc);
            scatter_one(p1.z, p1.w, p2.x, q4.z, ci, macc);
            scatter_one(p2.y, p2.z, p2.w, q4.w, ci, macc);
        } else {
            for (long k = i; k < N; k++)
                scatter_one(pos[3*k], pos[3*k+1], pos[3*k+2], charges[k], ci, macc);
        }
    }

    // wave pre-reduce: lane l += lane l^32 -> lower 32 lanes hold pair sums
    #pragma unroll
    for (int c = 0; c < 32; c++) {
        macc[c].x += __shfl_xor(macc[c].x, 32);
        macc[c].y += __shfl_xor(macc[c].y, 32);
    }
    int t = threadIdx.x;
    int row = (t >> 6) * 32 + (t & 31);
    if ((t & 32) == 0) {
        int sw = t & 31;
        #pragma unroll
        for (int c = 0; c < 32; c++) red[row][c ^ sw] = macc[c];
    }
    __syncthreads();
    int p = t & 31, g = t >> 5;
    f32x2 sum = splat2(0.0f);
    #pragma unroll
    for (int i = 0; i < 16; i++) {
        int r = g*16 + i;
        sum += red[r][p ^ (r & 31)];
    }
    red2[g][p] = sum;
    __syncthreads();
    if (t < NCELL) {
        const float* r2 = (const float*)&red2[0][0];
        int pair = t >> 1, comp = t & 1;
        float s = 0.0f;
        #pragma unroll
        for (int gg = 0; gg < 8; gg++) s += r2[(gg*32 + pair)*2 + comp];
        partial[(long)blockIdx.x * NCELL + t] = s;   // plain store, no atomic
    }
}

// ---------- kernel B: deterministic partial-reduce + k-space filter ----------
// mesh'[r] = sum_{r'} G[(r-r') mod 4] mesh[r'];  no 1/64 (backward rfft, forward irfft)

__global__ __launch_bounds__(256) void reduce_filter_kernel(
        const float* __restrict__ partial, int nb,
        const float* __restrict__ cell, const float* __restrict__ sigma2p,
        float* __restrict__ mesh_out) {
    __shared__ float4 redA[16][16];
    __shared__ float mm[64];
    __shared__ float gr[64];
    int t = threadIdx.x;

    // fixed-order sum of per-block partials (nb blocks x 64 cells)
    int c4 = t & 15, g = t >> 4;             // c4: float4 column, g: block-phase
    float4 v = make_float4(0.f, 0.f, 0.f, 0.f);
    const float4* p4 = (const float4*)partial;
    for (int b = g; b < nb; b += 16) {
        float4 x = p4[b*16 + c4];
        v.x += x.x; v.y += x.y; v.z += x.z; v.w += x.w;
    }
    redA[g][c4] = v;
    __syncthreads();
    if (t < 16) {
        float4 tot = make_float4(0.f, 0.f, 0.f, 0.f);
        #pragma unroll
        for (int gg = 0; gg < 16; gg++) {
            float4 x = redA[gg][t];
            tot.x += x.x; tot.y += x.y; tot.z += x.z; tot.w += x.w;
        }
        ((float4*)mm)[t] = tot;
    }
    __syncthreads();

    // real-space Green's function of the smeared-Coulomb k-filter
    if (t < 64) {
        float ci[9]; inv3x3(cell, ci);
        float s2 = sigma2p[0];
        const float twopi = 6.2831853071795864769f;
        float G0x = twopi*ci[0], G0y = twopi*ci[3], G0z = twopi*ci[6];
        float G1x = twopi*ci[1], G1y = twopi*ci[4], G1z = twopi*ci[7];
        float G2x = twopi*ci[2], G2y = twopi*ci[5], G2z = twopi*ci[8];
        int dx = t >> 4, dy = (t >> 2) & 3, dz = t & 3;
        float acc = 0.0f;
        for (int a = 0; a < 4; a++) {
            float fa = (a < 2) ? (float)a : (float)(a - 4);
            for (int b = 0; b < 4; b++) {
                float fb = (b < 2) ? (float)b : (float)(b - 4);
                for (int c = 0; c < 4; c++) {
                    if ((a | b | c) == 0) continue;
                    float fc = (c < 2) ? (float)c : (float)(c - 4);
                    float kx = fa*G0x + fb*G1x + fc*G2x;
                    float ky = fa*G0y + fb*G1y + fc*G2y;
                    float kz = fa*G0z + fb*G1z + fc*G2z;
                    float k2 = kx*kx + ky*ky + kz*kz;
                    float K  = expf(-k2 * s2 * 0.5f) / k2;
                    int ph = (a*dx + b*dy + c*dz) & 3;
                    float cs = (ph == 0) ? 1.0f : ((ph == 2) ? -1.0f : 0.0f);
                    acc += K * cs;
                }
            }
        }
        gr[t] = acc;
    }
    __syncthreads();
    if (t < 64) {
        int dx = t >> 4, dy = (t >> 2) & 3, dz = t & 3;
        float o = 0.0f;
        for (int s = 0; s < 64; s++) {
            int sx = s >> 4, sy = (s >> 2) & 3, sz = s & 3;
            int d = ((dx - sx) & 3)*16 + ((dy - sy) & 3)*4 + ((dz - sz) & 3);
            o += gr[d] * mm[s];
        }
        mesh_out[t] = o;
    }
}

// ---------- kernel C: gather (packed) + pk-MLP, per-block plain store ----------

__device__ __forceinline__ float pot_one(float px, float py, float pz,
                                         const float* __restrict__ ci,
                                         const f32x2* __restrict__ mf2,
                                         float* __restrict__ Xo, float* __restrict__ Yo,
                                         float* __restrict__ Zo) {
    float fx = px*ci[0] + py*ci[3] + pz*ci[6];
    float fy = px*ci[1] + py*ci[4] + pz*ci[7];
    float fz = px*ci[2] + py*ci[5] + pz*ci[8];
    axis_w4(fx*(float)NSM, Xo);
    axis_w4(fy*(float)NSM, Yo);
    axis_w4(fz*(float)NSM, Zo);
    f32x2 a01 = splat2(0.0f), a23 = splat2(0.0f);
    #pragma unroll
    for (int x = 0; x < 4; x++) {
        #pragma unroll
        for (int y = 0; y < 4; y++) {
            f32x2 w2 = splat2(Xo[x] * Yo[y]);
            a01 = pkfma(w2, mf2[x*8 + y*2    ], a01);
            a23 = pkfma(w2, mf2[x*8 + y*2 + 1], a23);
        }
    }
    return a01.x*Zo[0] + a01.y*Zo[1] + a23.x*Zo[2] + a23.y*Zo[3];
}

__global__ __launch_bounds__(256) void gather_mlp_kernel(
        const float* __restrict__ pos, const float* __restrict__ cell,
        const float* __restrict__ charges,
        const float* __restrict__ W1, const float* __restrict__ b1,
        const float* __restrict__ W2, const float* __restrict__ b2,
        const float* __restrict__ W3, const float* __restrict__ b3,
        const float* __restrict__ meshf, float* __restrict__ bsum, int N) {
    __shared__ f32x2 mf2[32];
    __shared__ float wavesum[4];
    if (threadIdx.x < 32) mf2[threadIdx.x] = ((const f32x2*)meshf)[threadIdx.x];
    float ci[9]; inv3x3(cell, ci);

    float w1r0[10], w1r1[10], b1r[10], w2r[10][10], b2r[10], w3r[10];
    #pragma unroll
    for (int j = 0; j < 10; j++) {
        w1r0[j] = W1[j]; w1r1[j] = W1[10 + j];
        b1r[j] = b1[j];  b2r[j] = b2[j]; w3r[j] = W3[j];
    }
    #pragma unroll
    for (int i = 0; i < 10; i++) {
        #pragma unroll
        for (int j = 0; j < 10; j++) w2r[i][j] = W2[10*i + j];
    }
    float b3r = b3[0];
    __syncthreads();

    long t4 = (long)blockIdx.x * blockDim.x + threadIdx.x;
    long i0 = t4 * 4;
    float ysum = 0.0f;

    if (i0 + 3 < N) {
        const float4* posv = (const float4*)pos;
        float4 p0 = posv[3*t4], p1 = posv[3*t4+1], p2 = posv[3*t4+2];
        float4 q4 = ((const float4*)charges)[t4];

        float X0[4],Y0[4],Z0[4], X1[4],Y1[4],Z1[4], X2[4],Y2[4],Z2[4], X3[4],Y3[4],Z3[4];
        float pt0 = pot_one(p0.x, p0.y, p0.z, ci, mf2, X0, Y0, Z0);
        float pt1 = pot_one(p0.w, p1.x, p1.y, ci, mf2, X1, Y1, Z1);
        float pt2 = pot_one(p1.z, p1.w, p2.x, ci, mf2, X2, Y2, Z2);
        float pt3 = pot_one(p2.y, p2.z, p2.w, ci, mf2, X3, Y3, Z3);

        f32x2 q01; q01.x = q4.x; q01.y = q4.y;
        f32x2 q23; q23.x = q4.z; q23.y = q4.w;
        f32x2 pA;  pA.x = pt0;  pA.y = pt1;
        f32x2 pB;  pB.x = pt2;  pB.y = pt3;

        f32x2 h1a[10], h1b[10];
        #pragma unroll
        for (int j = 0; j < 10; j++) {
            f32x2 ta = pkfma(pA, splat2(w1r1[j]), splat2(b1r[j]));
            ta = pkfma(q01, splat2(w1r0[j]), ta);
            h1a[j] = tanh2v(ta);
            f32x2 tb = pkfma(pB, splat2(w1r1[j]), splat2(b1r[j]));
            tb = pkfma(q23, splat2(w1r0[j]), tb);
            h1b[j] = tanh2v(tb);
        }
        f32x2 h2a[10], h2b[10];
        #pragma unroll
        for (int j = 0; j < 10; j++) {
            f32x2 aa = splat2(b2r[j]), ab = splat2(b2r[j]);
            #pragma unroll
            for (int i = 0; i < 10; i++) {
                f32x2 w = splat2(w2r[i][j]);
                aa = pkfma(h1a[i], w, aa);
                ab = pkfma(h1b[i], w, ab);
            }
            h2a[j] = tanh2v(aa);
            h2b[j] = tanh2v(ab);
        }
        f32x2 ya = splat2(b3r), yb = splat2(b3r);
        #pragma unroll
        for (int j = 0; j < 10; j++) {
            f32x2 w = splat2(w3r[j]);
            ya = pkfma(h2a[j], w, ya);
            yb = pkfma(h2b[j], w, yb);
        }
        ysum = ya.x + ya.y + yb.x + yb.y;
    } else if (i0 < N) {
        for (long k = i0; k < N; k++) {
            float X[4], Y[4], Z[4];
            float pt = pot_one(pos[3*k], pos[3*k+1], pos[3*k+2], ci, mf2, X, Y, Z);
            float q  = charges[k];
            float h1[10], h2[10];
            #pragma unroll
            for (int j = 0; j < 10; j++)
                h1[j] = tanh1(fmaf(q, w1r0[j], fmaf(pt, w1r1[j], b1r[j])));
            #pragma unroll
            for (int j = 0; j < 10; j++) {
                float acc = b2r[j];
                #pragma unroll
                for (int i = 0; i < 10; i++) acc = fmaf(h1[i], w2r[i][j], acc);
                h2[j] = tanh1(acc);
            }
            float y = b3r;
            #pragma unroll
            for (int j = 0; j < 10; j++) y = fmaf(h2[j], w3r[j], y);
            ysum += y;
        }
    }

    ysum += __shfl_down(ysum, 32);
    ysum += __shfl_down(ysum, 16);
    ysum += __shfl_down(ysum, 8);
    ysum += __shfl_down(ysum, 4);
    ysum += __shfl_down(ysum, 2);
    ysum += __shfl_down(ysum, 1);
    int wid  = threadIdx.x >> 6;
    int lane = threadIdx.x & 63;
    if (lane == 0) wavesum[wid] = ysum;
    __syncthreads();
    if (threadIdx.x == 0)
        bsum[blockIdx.x] = wavesum[0] + wavesum[1] + wavesum[2] + wavesum[3];
}

// ---------- kernel D: deterministic final sum ----------

__global__ __launch_bounds__(256) void final_sum_kernel(
        const float* __restrict__ bsum, int nb, float* __restrict__ out) {
    __shared__ float wavesum[4];
    float s = 0.0f;
    for (int i = threadIdx.x; i < nb; i += 256) s += bsum[i];
    s += __shfl_down(s, 32);
    s += __shfl_down(s, 16);
    s += __shfl_down(s, 8);
    s += __shfl_down(s, 4);
    s += __shfl_down(s, 2);
    s += __shfl_down(s, 1);
    int wid  = threadIdx.x >> 6;
    int lane = threadIdx.x & 63;
    if (lane == 0) wavesum[wid] = s;
    __syncthreads();
    if (threadIdx.x == 0)
        out[0] = wavesum[0] + wavesum[1] + wavesum[2] + wavesum[3];
}

// ---------- launch ----------

extern "C" void kernel_launch(void* const* d_in, const int* in_sizes, int n_in,
                              void* d_out, int out_size, void* d_ws, size_t ws_size,
                              hipStream_t stream) {
    const float* pos     = (const float*)d_in[0];
    const float* cell    = (const float*)d_in[1];
    const float* charges = (const float*)d_in[2];
    const float* sigma2  = (const float*)d_in[3];
    const float* W1 = (const float*)d_in[4];
    const float* b1 = (const float*)d_in[5];
    const float* W2 = (const float*)d_in[6];
    const float* b2 = (const float*)d_in[7];
    const float* W3 = (const float*)d_in[8];
    const float* b3 = (const float*)d_in[9];
    int N = in_sizes[2];                         // charges (N,1)

    int ga_blocks = (int)(((long)N + 1023) / 1024);   // 4 particles/thread

    // ws layout: partial[sc*64] | meshf[64] | bsum[ga_blocks]
    long cap    = (long)(ws_size / sizeof(float));
    long budget = cap - 64 - (long)ga_blocks;
    int  sc     = 1024;
    if ((long)sc * NCELL > budget) sc = (int)(budget / NCELL);
    if (sc < 1) sc = 1;

    float* partial = (float*)d_ws;
    float* meshf   = partial + (long)sc * NCELL;
    float* bsum    = meshf + NCELL;

    scatter_kernel<<<sc, 256, 0, stream>>>(pos, cell, charges, partial, N);
    reduce_filter_kernel<<<1, 256, 0, stream>>>(partial, sc, cell, sigma2, meshf);
    gather_mlp_kernel<<<ga_blocks, 256, 0, stream>>>(pos, cell, charges,
                                                     W1, b1, W2, b2, W3, b3,
                                                     meshf, bsum, N);
    final_sum_kernel<<<1, 256, 0, stream>>>(bsum, ga_blocks, (float*)d_out);
}